// Round 11
// baseline (183.167 us; speedup 1.0000x reference)
//
#include <hip/hip_runtime.h>
#include <hip/hip_bf16.h>
#include <cstdint>
#include <cstddef>

// AFT forward, MI355X. Pipeline (4 dispatches):
//  1. prep    : data f32->bf16 | P=exp(pos_bias) bf16 | W_qkv^T split into
//               WqT + WkvTi (k/v interleaved 32-row groups [16 k | 16 v]) | W_out^T
//  2. qkv256  : grid-union 192 blocks, 256^2 tile, 8 waves, dbuf LDS,
//               single barrier/K-tile, setprio:
//               blocks [0,64)  : q f32 = data_bf @ WqT^T + b_q
//               blocks [64,192): kv GEMM -> BndT[rr][t]=exp(k)*v, [rr+16][t]=exp(k)
//  3. aft256  : 128 blocks, 256^2: Y bf16 = sigmoid(q)*[P@EKV]/[P@EK]
//  4. GEMM3   : out f32 = Y @ W_out^T + b_out   (proven 128^2 m97 structure)
// 256^2 body: BK=32, 2 LDS buffers (64 KB), stage(t+1) issued before compute(t),
// one __syncthreads()/K-tile (its implicit vmcnt drain waits on ~1-tile-old loads).
// Race-free by construction: buf^1 writes issue only after the barrier at which
// all buf^1 reads (tile t-1) completed. Same MFMA K-order => bit-identical output.

typedef __bf16 bf16_t;
typedef __attribute__((ext_vector_type(8))) __bf16 bf16x8;
typedef __attribute__((ext_vector_type(4))) __bf16 bf16x4;
typedef __attribute__((ext_vector_type(4))) float floatx4;

#define T_DIM 1024
#define B_DIM 4
#define D_DIM 1024
#define R_DIM (T_DIM * B_DIM)   // 4096
#define N_QKV (3 * D_DIM)       // 3072
#define N_ND  (2 * R_DIM)       // 8192

// ---------------- prep: all input conversions in one dispatch ----------------
__global__ void k_prep(const float* __restrict__ data, const float* __restrict__ pos_bias,
                       const float* __restrict__ W_qkv, const float* __restrict__ W_out,
                       bf16_t* __restrict__ data_bf, bf16_t* __restrict__ P_bf,
                       bf16_t* __restrict__ WqT, bf16_t* __restrict__ WkvTi,
                       bf16_t* __restrict__ WoutT) {
    __shared__ float s[32][33];
    const int bid = blockIdx.x, tid = threadIdx.x;
    if (bid < 5120) {
        const float* in = (bid < 4096) ? data : pos_bias;
        bf16_t* out = (bid < 4096) ? data_bf : P_bf;
        int bb = (bid < 4096) ? bid : bid - 4096;
        int do_exp = (bid >= 4096);
        int i = (bb * 256 + tid) * 4;
        float4 v = *reinterpret_cast<const float4*>(in + i);
        bf16x4 o;
        if (do_exp) {
            o[0] = (bf16_t)__expf(v.x); o[1] = (bf16_t)__expf(v.y);
            o[2] = (bf16_t)__expf(v.z); o[3] = (bf16_t)__expf(v.w);
        } else {
            o[0] = (bf16_t)v.x; o[1] = (bf16_t)v.y;
            o[2] = (bf16_t)v.z; o[3] = (bf16_t)v.w;
        }
        *reinterpret_cast<bf16x4*>(out + i) = o;
    } else if (bid < 8192) {
        int idx = bid - 5120;                       // 3072 blocks = 96 x 32
        int n0 = (idx % 96) * 32, k0 = (idx / 96) * 32;
        int tx = tid & 31, ty = tid >> 5;
#pragma unroll
        for (int i = 0; i < 4; ++i)
            s[ty + i * 8][tx] = W_qkv[(size_t)(k0 + ty + i * 8) * N_QKV + n0 + tx];
        __syncthreads();
#pragma unroll
        for (int i = 0; i < 4; ++i) {
            int n = n0 + ty + i * 8;
            bf16_t val = (bf16_t)s[tx][ty + i * 8];
            bf16_t* dst; size_t row;
            if (n < 1024)      { dst = WqT;   row = n; }
            else if (n < 2048) { int d = n - 1024; dst = WkvTi; row = ((d >> 4) << 5) + (d & 15); }
            else               { int d = n - 2048; dst = WkvTi; row = ((d >> 4) << 5) + (d & 15) + 16; }
            dst[row * D_DIM + k0 + tx] = val;
        }
    } else {
        int idx = bid - 8192;                       // 1024 blocks = 32 x 32
        int n0 = (idx % 32) * 32, k0 = (idx / 32) * 32;
        int tx = tid & 31, ty = tid >> 5;
#pragma unroll
        for (int i = 0; i < 4; ++i)
            s[ty + i * 8][tx] = W_out[(size_t)(k0 + ty + i * 8) * D_DIM + n0 + tx];
        __syncthreads();
#pragma unroll
        for (int i = 0; i < 4; ++i)
            WoutT[(size_t)(n0 + ty + i * 8) * D_DIM + k0 + tx] = (bf16_t)s[tx][ty + i * 8];
    }
}

// ---------------- shared helpers ----------------
__device__ __forceinline__ void gload16(const bf16_t* src, bf16_t* dst) {
    __builtin_amdgcn_global_load_lds(
        (const __attribute__((address_space(1))) void*)src,
        (__attribute__((address_space(3))) void*)dst, 16, 0, 0);
}

// ======== 256^2 / BK=32 / 8-wave double-buffered body ========
// Stage one 256x32 A-tile + B-tile (4 gloads/thread). Linear LDS [256][32].
__device__ __forceinline__ void stage32(const bf16_t* A0, int sA,
                                        const bf16_t* B0, int sB, int k0,
                                        bf16_t* AsB, bf16_t* BsB, int wid, int lane) {
    const int r0 = wid * 16 + (lane >> 2);
    const int c = (lane & 3) * 8;
#pragma unroll
    for (int j = 0; j < 2; ++j) {
        gload16(A0 + (size_t)(r0 + j * 128) * sA + k0 + c, AsB + j * 4096 + wid * 512);
        gload16(B0 + (size_t)(r0 + j * 128) * sB + k0 + c, BsB + j * 4096 + wid * 512);
    }
}

// One K-tile of MFMAs: wave (wm,wn) computes 128x64 out, acc[8][4].
__device__ __forceinline__ void tile32(const bf16_t* As, const bf16_t* Bs,
                                       int wm, int wn, int lane, floatx4 (&acc)[8][4]) {
    const int lr = lane & 15, k0 = (lane >> 4) * 8;
    bf16x8 a[8], b[4];
#pragma unroll
    for (int mf = 0; mf < 8; ++mf)
        a[mf] = *reinterpret_cast<const bf16x8*>(As + (wm * 128 + mf * 16 + lr) * 32 + k0);
#pragma unroll
    for (int nf = 0; nf < 4; ++nf)
        b[nf] = *reinterpret_cast<const bf16x8*>(Bs + (wn * 64 + nf * 16 + lr) * 32 + k0);
    __builtin_amdgcn_s_setprio(1);
#pragma unroll
    for (int mf = 0; mf < 8; ++mf)
#pragma unroll
        for (int nf = 0; nf < 4; ++nf)
            acc[mf][nf] = __builtin_amdgcn_mfma_f32_16x16x32_bf16(a[mf], b[nf], acc[mf][nf], 0, 0, 0);
    __builtin_amdgcn_s_setprio(0);
}

#define PRE256()                                                      \
    __shared__ __align__(16) bf16_t As0[256 * 32], Bs0[256 * 32];     \
    __shared__ __align__(16) bf16_t As1[256 * 32], Bs1[256 * 32];     \
    const int tid = threadIdx.x;                                      \
    const int wid = tid >> 6, lane = tid & 63;                        \
    const int wm = wid >> 2, wn = wid & 3;                            \
    const int lr = lane & 15, lg = lane >> 4;                         \
    floatx4 acc[8][4];                                                \
    _Pragma("unroll") for (int mf = 0; mf < 8; ++mf)                  \
        _Pragma("unroll") for (int nf = 0; nf < 4; ++nf)              \
            acc[mf][nf] = (floatx4){0.f, 0.f, 0.f, 0.f};

// K=1024: 32 K-tiles, unrolled x2 so buffers are static. stage(t+1) issued
// BEFORE compute(t); one __syncthreads() per K-tile drains the wave's own
// gloads (issued a full tile earlier) then syncs.
#define LOOP256(Ab, sA, Bb, sB)                                       \
    stage32(Ab, sA, Bb, sB, 0, As0, Bs0, wid, lane);                  \
    __syncthreads();                                                  \
    for (int t2 = 0; t2 < 16; ++t2) {                                 \
        stage32(Ab, sA, Bb, sB, t2 * 64 + 32, As1, Bs1, wid, lane);   \
        tile32(As0, Bs0, wm, wn, lane, acc);                          \
        __syncthreads();                                              \
        if (t2 < 15)                                                  \
            stage32(Ab, sA, Bb, sB, t2 * 64 + 64, As0, Bs0, wid, lane);\
        tile32(As1, Bs1, wm, wn, lane, acc);                          \
        __syncthreads();                                              \
    }

// ---------------- qkv grid-union, 256^2 ----------------
// blocks [0,64):   q GEMM  (4096x1024), writes q_buf f32
// blocks [64,192): kv GEMM (2048x1024 per b), writes BndT bf16 num/den
__global__ __launch_bounds__(512, 1)
void k_qkv256(const bf16_t* __restrict__ data_bf, const bf16_t* __restrict__ WqT,
              const bf16_t* __restrict__ WkvTi, const float* __restrict__ b_qkv,
              float* __restrict__ q_buf, bf16_t* __restrict__ BndT) {
    PRE256()
    const int bid = blockIdx.x;
    if (bid < 64) {
        const int row0 = (bid >> 2) * 256, col0 = (bid & 3) * 256;
        const bf16_t* Ab = data_bf + (size_t)row0 * D_DIM;
        const bf16_t* Bb = WqT + (size_t)col0 * D_DIM;
        LOOP256(Ab, D_DIM, Bb, D_DIM)
#pragma unroll
        for (int nf = 0; nf < 4; ++nf) {
            int col = col0 + wn * 64 + nf * 16 + lr;
            float bv = b_qkv[col];
#pragma unroll
            for (int mf = 0; mf < 8; ++mf) {
                int row = row0 + wm * 128 + mf * 16 + lg * 4;
                float* Cp = q_buf + (size_t)row * D_DIM + col;
#pragma unroll
                for (int j = 0; j < 4; ++j) Cp[(size_t)j * D_DIM] = acc[mf][nf][j] + bv;
            }
        }
    } else {
        const int idx = bid - 64;
        const int b = idx >> 5;
        const int row0 = ((idx & 31) >> 2) * 256;     // WkvTi rows (8 tiles)
        const int col0 = (idx & 3) * 256;             // t (4 tiles)
        const bf16_t* Ab = WkvTi + (size_t)row0 * D_DIM;
        const bf16_t* Bb = data_bf + ((size_t)col0 * 4 + b) * D_DIM;  // row stride 4096
        LOOP256(Ab, D_DIM, Bb, 4 * D_DIM)
        // epilogue: mf pairs (2p, 2p+1) = (k, v) for the same d
#pragma unroll
        for (int p = 0; p < 4; ++p) {
#pragma unroll
            for (int j = 0; j < 4; ++j) {
                int gk = row0 + wm * 128 + p * 32 + lg * 4 + j;
                int d = ((gk >> 5) << 4) + (lg * 4 + j);
                float bk = b_qkv[D_DIM + d];
                float bvv = b_qkv[2 * D_DIM + d];
                int r = b * D_DIM + d;
                int rr = ((r >> 4) << 5) + (r & 15);
#pragma unroll
                for (int nf = 0; nf < 4; ++nf) {
                    int t = col0 + wn * 64 + nf * 16 + lr;
                    float e = __expf(acc[2 * p][nf][j] + bk);
                    float vv = acc[2 * p + 1][nf][j] + bvv;
                    BndT[(size_t)rr * T_DIM + t] = (bf16_t)(e * vv);       // num
                    BndT[(size_t)(rr + 16) * T_DIM + t] = (bf16_t)e;       // den
                }
            }
        }
    }
}

// ---------------- aft 256^2: Y = sigmoid(q) * (P@EKV)/(P@EK) ----------------
__global__ __launch_bounds__(512, 1)
void k_aft256(const bf16_t* __restrict__ P_bf, const bf16_t* __restrict__ BndT,
              const float* __restrict__ q, bf16_t* __restrict__ Y) {
    PRE256()
    const int bid = blockIdx.x;
    const int row0 = (bid >> 5) * 256;                // t rows (4 tiles)
    const int col0 = (bid & 31) * 256;                // BndT cols (32 tiles)
    const bf16_t* Ab = P_bf + (size_t)row0 * T_DIM;
    const bf16_t* Bb = BndT + (size_t)col0 * T_DIM;
    LOOP256(Ab, T_DIM, Bb, T_DIM)
    // epilogue: nf pairs (2p, 2p+1) = num/den of the same 16 cols
#pragma unroll
    for (int p = 0; p < 2; ++p) {
        int ncol = col0 + wn * 64 + p * 32 + lr;
        int r = ((ncol >> 5) << 4) + lr;              // r = b*1024 + d
#pragma unroll
        for (int mf = 0; mf < 8; ++mf) {
            int trow = row0 + wm * 128 + mf * 16 + lg * 4;
#pragma unroll
            for (int j = 0; j < 4; ++j) {
                int t = trow + j;
                float num = acc[mf][2 * p][j];
                float den = acc[mf][2 * p + 1][j];
                float qv = q[(size_t)t * R_DIM + r];
                float y = num / (den * (1.0f + __expf(-qv)));
                Y[(size_t)t * R_DIM + r] = (bf16_t)y;
            }
        }
    }
}

// ======== proven 128^2 m97 body (gemm3) ========
__device__ __forceinline__ void mfma_loop(
    const bf16_t* __restrict__ aSrc0, const bf16_t* __restrict__ aSrc1,
    const bf16_t* __restrict__ bSrc0, const bf16_t* __restrict__ bSrc1,
    bf16_t* As, bf16_t* Bs, int wid, int lane, int K, floatx4 (&acc)[4][4]) {
    const int lr = lane & 15, kq = (lane >> 4) * 8;
    const int wm = wid >> 1, wn = wid & 1;
    for (int kt = 0; kt < K; kt += 32) {
        __syncthreads();
        gload16(aSrc0 + kt, As + wid * 1024);
        gload16(aSrc1 + kt, As + wid * 1024 + 512);
        gload16(bSrc0 + kt, Bs + wid * 1024);
        gload16(bSrc1 + kt, Bs + wid * 1024 + 512);
        __syncthreads();
        bf16x8 af[4], bfr[4];
#pragma unroll
        for (int m = 0; m < 4; ++m)
            af[m] = *reinterpret_cast<const bf16x8*>(As + (wm * 64 + m * 16 + lr) * 32 + kq);
#pragma unroll
        for (int n = 0; n < 4; ++n)
            bfr[n] = *reinterpret_cast<const bf16x8*>(Bs + (wn * 64 + n * 16 + lr) * 32 + kq);
#pragma unroll
        for (int m = 0; m < 4; ++m)
#pragma unroll
            for (int n = 0; n < 4; ++n)
                acc[m][n] = __builtin_amdgcn_mfma_f32_16x16x32_bf16(af[m], bfr[n], acc[m][n], 0, 0, 0);
    }
}

__global__ __launch_bounds__(256)
void k_gemm(const bf16_t* __restrict__ A, const bf16_t* __restrict__ BT,
            const float* __restrict__ bias, float* __restrict__ C,
            int M, int N, int K) {
    __shared__ __align__(16) bf16_t As[128 * 32];
    __shared__ __align__(16) bf16_t Bs[128 * 32];
    const int tid = threadIdx.x;
    const int wid = tid >> 6, lane = tid & 63;
    const int wm = wid >> 1, wn = wid & 1;
    floatx4 acc[4][4];
#pragma unroll
    for (int m = 0; m < 4; ++m)
#pragma unroll
        for (int n = 0; n < 4; ++n) acc[m][n] = (floatx4){0.f, 0.f, 0.f, 0.f};
    const int lr = lane & 15;
    const int e0 = wid * 1024 + lane * 8;
    const int ra0 = e0 >> 5, kk0 = e0 & 31;
    const int ra1 = (e0 + 512) >> 5, kk1 = (e0 + 512) & 31;
    const int lg = lane >> 4;
    const int row0 = blockIdx.x * 128, col0 = blockIdx.y * 128;
    mfma_loop(A + (size_t)(row0 + ra0) * K + kk0, A + (size_t)(row0 + ra1) * K + kk1,
              BT + (size_t)(col0 + ra0) * K + kk0, BT + (size_t)(col0 + ra1) * K + kk1,
              As, Bs, wid, lane, K, acc);
#pragma unroll
    for (int n = 0; n < 4; ++n) {
        int col = col0 + wn * 64 + n * 16 + lr;
        float bv = bias ? bias[col] : 0.0f;
#pragma unroll
        for (int m = 0; m < 4; ++m) {
            int row = row0 + wm * 64 + m * 16 + lg * 4;
            float* Cp = C + (size_t)row * N + col;
#pragma unroll
            for (int j = 0; j < 4; ++j) Cp[(size_t)j * N] = acc[m][n][j] + bv;
        }
    }
}

extern "C" void kernel_launch(void* const* d_in, const int* in_sizes, int n_in,
                              void* d_out, int out_size, void* d_ws, size_t ws_size,
                              hipStream_t stream) {
    const float* data     = (const float*)d_in[0];  // [T,B,D]
    const float* W_qkv    = (const float*)d_in[1];  // [D,3D]
    const float* b_qkv    = (const float*)d_in[2];  // [3D]
    const float* pos_bias = (const float*)d_in[3];  // [T,T]
    const float* W_out    = (const float*)d_in[4];  // [D,D]
    const float* b_out    = (const float*)d_in[5];  // [D]
    float* out = (float*)d_out;

    char* ws = (char*)d_ws;
    const size_t MB = 1024 * 1024;
    bf16_t* data_bf = (bf16_t*)(ws + 0);         //  8 MB [4096][1024]
    bf16_t* WqT     = (bf16_t*)(ws + 8 * MB);    //  2 MB [1024][1024]
    bf16_t* WkvTi   = (bf16_t*)(ws + 10 * MB);   //  4 MB [2048][1024] interleaved
    bf16_t* WoutT   = (bf16_t*)(ws + 14 * MB);   //  2 MB [1024][1024]
    bf16_t* P_bf    = (bf16_t*)(ws + 16 * MB);   //  2 MB [1024][1024]
    float*  q_buf   = (float*) (ws + 18 * MB);   // 16 MB q[(t*4+b)*1024+d]
    bf16_t* BndT    = (bf16_t*)(ws + 34 * MB);   // 16 MB [8192][1024] interleaved
    bf16_t* Y       = (bf16_t*)(ws + 0);         //  8 MB, aliases data_bf (dead after qkv)

    // 1. prep
    k_prep<<<dim3(9216), dim3(256), 0, stream>>>(data, pos_bias, W_qkv, W_out,
                                                 data_bf, P_bf, WqT, WkvTi, WoutT);
    // 2. q + kv grid-union GEMM, 256^2
    k_qkv256<<<dim3(192), dim3(512), 0, stream>>>(data_bf, WqT, WkvTi, b_qkv,
                                                  q_buf, BndT);
    // 3. aft 256^2: Y = sigmoid(q) * (P@EKV) / (P@EK)
    k_aft256<<<dim3(128), dim3(512), 0, stream>>>(P_bf, BndT, q_buf, Y);
    // 4. out = Y @ W_out + b_out (128^2)
    k_gemm<<<dim3(R_DIM / 128, D_DIM / 128), dim3(256), 0, stream>>>(
        Y, WoutT, b_out, out, R_DIM, D_DIM, D_DIM);
}